// Round 18
// baseline (151.330 us; speedup 1.0000x reference)
//
#include <hip/hip_runtime.h>

#define NTOK 32768   // 8*64*64 tokens
#define CIN 192
#define C3 576
#define HEADS 8
#define HD 24

typedef __attribute__((ext_vector_type(8))) short bf16x8;
typedef __attribute__((ext_vector_type(16))) float f32x16;
typedef __attribute__((ext_vector_type(4))) unsigned int u32x4;

__device__ __forceinline__ float bf2f(unsigned int u) {
  union { unsigned int i; float f; } x; x.i = u << 16; return x.f;
}
__device__ __forceinline__ unsigned short f2bf(float f) {
  union { float f; unsigned int i; } x; x.f = f;
  unsigned int r = x.i + 0x7fffu + ((x.i >> 16) & 1u);
  return (unsigned short)(r >> 16);
}

// ---------------------------------------------------------------------------
// k_wfrag: fp32 W[O][192] -> bf16 MFMA-A-fragment-linear table.
// chunk g = ((otile*12 + kk)*2 + hi)*64 + olane holds W[otile*64+olane][kk*16+hi*8..+7]
// ---------------------------------------------------------------------------
__global__ __launch_bounds__(256) void k_wfrag(const float* __restrict__ W,
                                               unsigned short* __restrict__ Wf,
                                               int nchunk) {
  const int g = blockIdx.x * 256 + threadIdx.x;
  if (g >= nchunk) return;
  const int ol = g & 63, hi = (g >> 6) & 1, kk = (g >> 7) % 12, ot = g / 1536;
  const float* src = W + (size_t)(ot * 64 + ol) * CIN + kk * 16 + hi * 8;
  bf16x8 p;
#pragma unroll
  for (int e = 0; e < 8; ++e) p[e] = (short)f2bf(src[e]);
  *(bf16x8*)&Wf[(size_t)g * 8] = p;
}

// ---------------------------------------------------------------------------
// k_gemm_rr: Y[o,n] = bias[o] + sum_c W[o,c]*X[c,n], K=192 in registers.
// grid (512 n-tiles, 1, 2 batches); block stages X once, loops ALL ot_per
// o-tiles. A-frag loads are inline-asm global_load_dwordx4 issued 12-deep.
// One vmcnt(0) + sched_barrier per o-tile. CHAMPION CONFIG (r11/r16/r17)
// + T5: s_setprio(1) around the MFMA cluster — after the single barrier the
// waves drift to different o-phases (proj==qkv dur proved o-loop-independent
// per-block cost), which is the role-diversity regime where setprio pays.
// ---------------------------------------------------------------------------
template<int XBF, int OUTF32>
__global__ __launch_bounds__(256, 2) void k_gemm_rr(
    const void* __restrict__ Xv, const unsigned short* __restrict__ Wf0,
    const float* __restrict__ bias, void* __restrict__ Yv, int ot_per,
    long xbs, long ybs, long wbs)
{
  __shared__ __align__(16) unsigned short Xl[192][68];   // 26112 B
  const int tid = threadIdx.x;
  const int b = blockIdx.z;
  const int n0 = blockIdx.x * 64;
  const unsigned short* Wf = Wf0 + (size_t)b * wbs;

  if (XBF) {
    const unsigned short* X = (const unsigned short*)Xv + (size_t)b * xbs;
#pragma unroll
    for (int i = 0; i < 12; ++i) {
      const int g = tid + i * 256;
      const int c = g >> 4, nq = (g & 15) * 4;
      *(unsigned long long*)&Xl[c][nq] =
          *(const unsigned long long*)&X[(size_t)c * NTOK + n0 + nq];
    }
  } else {
    const float* X = (const float*)Xv + (size_t)b * xbs;
#pragma unroll
    for (int i = 0; i < 12; ++i) {
      const int g = tid + i * 256;
      const int c = g >> 4, nq = (g & 15) * 4;
      float4 v = *(const float4*)&X[(size_t)c * NTOK + n0 + nq];
      unsigned short p[4] = {f2bf(v.x), f2bf(v.y), f2bf(v.z), f2bf(v.w)};
      *(unsigned long long*)&Xl[c][nq] = *(unsigned long long*)p;
    }
  }
  __syncthreads();

  const int lane = tid & 63;
  const int wv = tid >> 6;
  const int o_w = (wv >> 1) * 32;
  const int n_w = (wv & 1) * 32;
  const int j = lane & 31;
  const int hi = lane >> 5;

  bf16x8 bfr[12];
#pragma unroll
  for (int kk = 0; kk < 12; ++kk)
#pragma unroll
    for (int e = 0; e < 8; ++e)
      bfr[kk][e] = (short)Xl[kk * 16 + hi * 8 + e][n_w + j];

  for (int it = 0; it < ot_per; ++it) {
    const int o0 = it * 64;
    const unsigned short* wp =
        Wf + ((size_t)it * 1536 + hi * 64 + o_w + j) * 8;

    // 12-deep pipelined A-frag loads (cannot be sunk by the scheduler)
    bf16x8 a[12];
#pragma unroll
    for (int kk = 0; kk < 12; ++kk) {
      unsigned long long ad = (unsigned long long)(wp + kk * 1024);
      asm volatile("global_load_dwordx4 %0, %1, off"
                   : "=v"(a[kk]) : "v"(ad));
    }
    asm volatile("s_waitcnt vmcnt(0)" ::: "memory");
    __builtin_amdgcn_sched_barrier(0);

    f32x16 acc0, acc1;
#pragma unroll
    for (int i = 0; i < 16; ++i) { acc0[i] = 0.f; acc1[i] = 0.f; }
    __builtin_amdgcn_s_setprio(1);
#pragma unroll
    for (int kp = 0; kp < 6; ++kp) {
      acc0 = __builtin_amdgcn_mfma_f32_32x32x16_bf16(a[2 * kp], bfr[2 * kp], acc0, 0, 0, 0);
      acc1 = __builtin_amdgcn_mfma_f32_32x32x16_bf16(a[2 * kp + 1], bfr[2 * kp + 1], acc1, 0, 0, 0);
    }
    __builtin_amdgcn_s_setprio(0);

    if (OUTF32) {
      float* Y = (float*)Yv + (size_t)b * ybs;
#pragma unroll
      for (int r = 0; r < 16; ++r) {
        const int row = o_w + (r & 3) + 8 * (r >> 2) + 4 * hi;
        Y[(size_t)(o0 + row) * NTOK + n0 + n_w + j] =
            acc0[r] + acc1[r] + bias[o0 + row];
      }
    } else {
      unsigned short* Y = (unsigned short*)Yv + (size_t)b * ybs;
#pragma unroll
      for (int r = 0; r < 16; ++r) {
        const int row = o_w + (r & 3) + 8 * (r >> 2) + 4 * hi;
        Y[(size_t)(o0 + row) * NTOK + n0 + n_w + j] =
            f2bf(acc0[r] + acc1[r] + bias[o0 + row]);
      }
    }
  }
}

// ---------------------------------------------------------------------------
// K2: depthwise 3x3x3, pad 1, bf16 in/out, fp32 math; grid.z = batch.
// Rolling-store form (r17): VALU-issue-bound at its structural floor.
// ---------------------------------------------------------------------------
__global__ __launch_bounds__(256, 4) void k_dwconv(
    const unsigned short* __restrict__ in0,   // [2][576][8][64][64] bf16
    const float* __restrict__ wdw,            // [576][27]
    const float* __restrict__ bdw,            // [576]
    unsigned short* __restrict__ out0)        // [2][576][8][64][64] bf16
{
  __shared__ __align__(16) unsigned short s[8][18][76];
  const int tid = threadIdx.x;
  const int ch = blockIdx.y;
  const int h0 = blockIdx.x * 16;
  const size_t boff = (size_t)blockIdx.z * C3 * NTOK;
  const unsigned short* inch = in0 + boff + (size_t)ch * NTOK;

  for (int r = tid; r < 144; r += 256) {
    const int t = r / 18, rr = r % 18;
    s[t][rr][7] = 0;
    s[t][rr][72] = 0;
  }
  for (int idx = tid; idx < 144 * 8; idx += 256) {
    const int row = idx >> 3, seg = idx & 7;
    const int t = row / 18, rr = row % 18;
    const int h = h0 + rr - 1;
    u32x4 v = {0u, 0u, 0u, 0u};
    if (h >= 0 && h < 64)
      v = *(const u32x4*)&inch[t * 4096 + h * 64 + seg * 8];
    *(u32x4*)&s[t][rr][8 + seg * 8] = v;
  }
  float wr[27];
#pragma unroll
  for (int i = 0; i < 27; ++i) {
    union { float f; int v; } u;
    u.f = wdw[ch * 27 + i];
    u.v = __builtin_amdgcn_readfirstlane(u.v);
    wr[i] = u.f;
  }
  union { float f; int v; } ub;
  ub.f = bdw[ch];
  ub.v = __builtin_amdgcn_readfirstlane(ub.v);
  const float bias = ub.f;
  __syncthreads();

  const int wloc = tid & 63;
  const int hl0 = (tid >> 6) * 4;
  unsigned short* outch = out0 + boff + (size_t)ch * NTOK;

  float acc[8][4];
#pragma unroll
  for (int t = 0; t < 8; ++t)
#pragma unroll
    for (int i = 0; i < 4; ++i) acc[t][i] = 0.f;

#pragma unroll
  for (int tt = 0; tt < 8; ++tt) {
    float v[6][3];
#pragma unroll
    for (int r = 0; r < 6; ++r)
#pragma unroll
      for (int c = 0; c < 3; ++c)
        v[r][c] = bf2f(s[tt][hl0 + r][7 + wloc + c]);
#pragma unroll
    for (int p = 0; p < 3; ++p) {
      const int t = tt + 1 - p;
      if (t < 0 || t > 7) continue;   // compile-time pruned
#pragma unroll
      for (int hi = 0; hi < 4; ++hi) {
        float a = 0.f;
#pragma unroll
        for (int dh = 0; dh < 3; ++dh)
#pragma unroll
          for (int dw = 0; dw < 3; ++dw)
            a += wr[p * 9 + dh * 3 + dw] * v[hi + dh][dw];
        acc[t][hi] += a;
      }
    }
    if (tt >= 1) {
      const int t = tt - 1;
#pragma unroll
      for (int hi = 0; hi < 4; ++hi)
        outch[t * 4096 + (h0 + hl0 + hi) * 64 + wloc] = f2bf(acc[t][hi] + bias);
    }
  }
#pragma unroll
  for (int hi = 0; hi < 4; ++hi)
    outch[7 * 4096 + (h0 + hl0 + hi) * 64 + wloc] = f2bf(acc[7][hi] + bias);
}

// ---------------------------------------------------------------------------
// K3: Gram via MFMA, direct-from-global; partials to Sp (no atomics/zero-init).
// grid (32 chunks, 8 heads, 2 batches).
// ---------------------------------------------------------------------------
__global__ __launch_bounds__(256) void k_gram(
    const unsigned short* __restrict__ post0, float* __restrict__ Sp0)
{
  const int tid = threadIdx.x;
  const int h = blockIdx.y;
  const unsigned short* post = post0 + (size_t)blockIdx.z * C3 * NTOK;
  float* Sp = Sp0 + (size_t)blockIdx.z * HEADS * 32 * 640;
  const int lane = tid & 63;
  const int wv = tid >> 6;
  const int c = lane & 31;
  const int off = (lane >> 5) * 8;
  const unsigned short* q = post + (size_t)(h * HD + c) * NTOK;
  const unsigned short* k = post + (size_t)(192 + h * HD + c) * NTOK;

  __shared__ float Sl[24][25];
  __shared__ float nl[48];
  for (int i = tid; i < 600; i += 256) ((float*)Sl)[i] = 0.f;
  if (tid < 48) nl[tid] = 0.f;
  __syncthreads();

  f32x16 acc;
#pragma unroll
  for (int i = 0; i < 16; ++i) acc[i] = 0.f;
  float sqq = 0.f, sqk = 0.f;

  const int base = blockIdx.x * 1024 + wv * 256 + off;
#pragma unroll
  for (int i = 0; i < 16; ++i) {
    const int n = base + i * 16;
    bf16x8 a = *(const bf16x8*)&q[n];
    bf16x8 b = *(const bf16x8*)&k[n];
#pragma unroll
    for (int e = 0; e < 8; ++e) {
      float fa = bf2f((unsigned short)a[e]);
      float fb = bf2f((unsigned short)b[e]);
      sqq += fa * fa;
      sqk += fb * fb;
    }
    acc = __builtin_amdgcn_mfma_f32_32x32x16_bf16(a, b, acc, 0, 0, 0);
  }

  sqq += __shfl_down(sqq, 32, 64);
  sqk += __shfl_down(sqk, 32, 64);
  if (lane < 32 && c < 24) {
    atomicAdd(&nl[c], sqq);
    atomicAdd(&nl[24 + c], sqk);
  }
  if (c < 24) {
#pragma unroll
    for (int r = 0; r < 16; ++r) {
      const int row = (r & 3) + 8 * (r >> 2) + 4 * (lane >> 5);
      if (row < 24) atomicAdd(&Sl[row][c], acc[r]);
    }
  }
  __syncthreads();
  float* outp = Sp + ((size_t)h * 32 + blockIdx.x) * 640;
  for (int i = tid; i < 576; i += 256) outp[i] = Sl[i / 24][i % 24];
  if (tid < 48) outp[576 + tid] = nl[tid];
}

// ---------------------------------------------------------------------------
// K4: reduce Sp; attn = softmax(S*temp/(|q||k|)); Wcomb = projW @ attn,
// written DIRECTLY in MFMA-fragment layout. grid (8 heads, 2 batches).
// ---------------------------------------------------------------------------
__global__ __launch_bounds__(256) void k_attn_wfrag(
    const float* __restrict__ Sp0, const float* __restrict__ temp,
    const float* __restrict__ projw, unsigned short* __restrict__ wfc0)
{
  const int h = blockIdx.x;
  const int tid = threadIdx.x;
  const float* base = Sp0 + (size_t)blockIdx.y * HEADS * 32 * 640 +
                      (size_t)h * 32 * 640;
  unsigned short* wfc = wfc0 + (size_t)blockIdx.y * 3 * 1536 * 8;

  __shared__ float Ssum[24][25];
  __shared__ float attn[24][25];
  __shared__ float nqs[24], nks[24];

  for (int i = tid; i < 576; i += 256) {
    float a = 0.f;
#pragma unroll 4
    for (int ch = 0; ch < 32; ++ch) a += base[(size_t)ch * 640 + i];
    Ssum[i / 24][i % 24] = a;
  }
  if (tid < 48) {
    float a = 0.f;
#pragma unroll 4
    for (int ch = 0; ch < 32; ++ch) a += base[(size_t)ch * 640 + 576 + tid];
    float nv = fmaxf(sqrtf(a), 1e-12f);
    if (tid < 24) nqs[tid] = nv; else nks[tid - 24] = nv;
  }
  __syncthreads();
  if (tid < 24) {
    const int c = tid;
    const float tmp = temp[h];
    float row[24];
    float m = -1e30f;
#pragma unroll
    for (int d = 0; d < 24; ++d) {
      float v = Ssum[c][d] / (nqs[c] * nks[d]) * tmp;
      row[d] = v;
      m = fmaxf(m, v);
    }
    float ssum = 0.f;
#pragma unroll
    for (int d = 0; d < 24; ++d) { float e = __expf(row[d] - m); row[d] = e; ssum += e; }
    const float inv = 1.f / ssum;
#pragma unroll
    for (int d = 0; d < 24; ++d) attn[c][d] = row[d] * inv;
  }
  __syncthreads();
  for (int e = tid; e < 192 * 24; e += 256) {
    const int o = e / 24, d = e % 24;
    float a = 0.f;
#pragma unroll
    for (int c = 0; c < 24; ++c) a += projw[o * 192 + h * 24 + c] * attn[c][d];
    const int c2 = h * 24 + d;
    const int ot = o >> 6, ol = o & 63;
    const int kk = c2 >> 4, hi = (c2 >> 3) & 1, e2 = c2 & 7;
    wfc[(size_t)((((ot * 12 + kk) * 2 + hi) * 64) + ol) * 8 + e2] = f2bf(a);
  }
}

// ---------------------------------------------------------------------------
extern "C" void kernel_launch(void* const* d_in, const int* in_sizes, int n_in,
                              void* d_out, int out_size, void* d_ws, size_t ws_size,
                              hipStream_t stream) {
  const float* x      = (const float*)d_in[0];
  const float* qkv_w  = (const float*)d_in[1];
  const float* qkv_b  = (const float*)d_in[2];
  const float* dw_w   = (const float*)d_in[3];
  const float* dw_b   = (const float*)d_in[4];
  const float* temp   = (const float*)d_in[5];
  const float* proj_w = (const float*)d_in[6];
  const float* proj_b = (const float*)d_in[7];
  float* out = (float*)d_out;

  char* ws = (char*)d_ws;
  size_t off = 0;
  unsigned short* post = (unsigned short*)(ws + off);
  off += (size_t)2 * C3 * NTOK * sizeof(unsigned short);       // 75.5 MB
  unsigned short* pre = (unsigned short*)(ws + off);
  off += (size_t)2 * C3 * NTOK * sizeof(unsigned short);       // 75.5 MB
  float* Sp = (float*)(ws + off);                              // [2][8*32][640]
  off += (size_t)2 * HEADS * 32 * 640 * sizeof(float);         // 1.31 MB
  off = (off + 255) & ~(size_t)255;
  unsigned short* wfq = (unsigned short*)(ws + off);           // qkv W frags
  off += (size_t)9 * 1536 * 8 * sizeof(unsigned short);        // 221 KB
  unsigned short* wfc = (unsigned short*)(ws + off);           // [2] wcomb frags
  off += (size_t)2 * 3 * 1536 * 8 * sizeof(unsigned short);    // 147 KB

  k_wfrag<<<54, 256, 0, stream>>>(qkv_w, wfq, 9 * 1536);

  k_gemm_rr<0, 0><<<dim3(512, 1, 2), 256, 0, stream>>>(
      x, wfq, qkv_b, pre, 9, (long)CIN * NTOK, (long)C3 * NTOK, 0);

  k_dwconv<<<dim3(4, C3, 2), 256, 0, stream>>>(pre, dw_w, dw_b, post);

  k_gram<<<dim3(32, HEADS, 2), 256, 0, stream>>>(post, Sp);

  k_attn_wfrag<<<dim3(HEADS, 2), 256, 0, stream>>>(Sp, temp, proj_w, wfc);

  k_gemm_rr<1, 1><<<dim3(512, 1, 2), 256, 0, stream>>>(
      post + (size_t)384 * NTOK, wfc, proj_b, out, 3,
      (long)C3 * NTOK, (long)CIN * NTOK, (long)3 * 1536 * 8);
}

// Round 19
// 145.116 us; speedup vs baseline: 1.0428x; 1.0428x over previous
//
#include <hip/hip_runtime.h>

#define NTOK 32768   // 8*64*64 tokens
#define CIN 192
#define C3 576
#define HEADS 8
#define HD 24

typedef __attribute__((ext_vector_type(8))) short bf16x8;
typedef __attribute__((ext_vector_type(16))) float f32x16;
typedef __attribute__((ext_vector_type(4))) unsigned int u32x4;

__device__ __forceinline__ float bf2f(unsigned int u) {
  union { unsigned int i; float f; } x; x.i = u << 16; return x.f;
}
__device__ __forceinline__ unsigned short f2bf(float f) {
  union { float f; unsigned int i; } x; x.f = f;
  unsigned int r = x.i + 0x7fffu + ((x.i >> 16) & 1u);
  return (unsigned short)(r >> 16);
}

// ---------------------------------------------------------------------------
// k_wfrag: fp32 W[O][192] -> bf16 MFMA-A-fragment-linear table.
// chunk g = ((otile*12 + kk)*2 + hi)*64 + olane holds W[otile*64+olane][kk*16+hi*8..+7]
// ---------------------------------------------------------------------------
__global__ __launch_bounds__(256) void k_wfrag(const float* __restrict__ W,
                                               unsigned short* __restrict__ Wf,
                                               int nchunk) {
  const int g = blockIdx.x * 256 + threadIdx.x;
  if (g >= nchunk) return;
  const int ol = g & 63, hi = (g >> 6) & 1, kk = (g >> 7) % 12, ot = g / 1536;
  const float* src = W + (size_t)(ot * 64 + ol) * CIN + kk * 16 + hi * 8;
  bf16x8 p;
#pragma unroll
  for (int e = 0; e < 8; ++e) p[e] = (short)f2bf(src[e]);
  *(bf16x8*)&Wf[(size_t)g * 8] = p;
}

// ---------------------------------------------------------------------------
// k_gemm_rr: Y[o,n] = bias[o] + sum_c W[o,c]*X[c,n], K=192 in registers.
// grid (512 n-tiles, 1, 2 batches); block stages X once, loops ALL ot_per
// o-tiles. A-frag loads are inline-asm global_load_dwordx4 issued 12-deep.
// One vmcnt(0) + sched_barrier per o-tile. CHAMPION CONFIG (r11/r16/r17;
// r18 A/B: setprio on the MFMA cluster is -4% here -> removed).
// ---------------------------------------------------------------------------
template<int XBF, int OUTF32>
__global__ __launch_bounds__(256, 2) void k_gemm_rr(
    const void* __restrict__ Xv, const unsigned short* __restrict__ Wf0,
    const float* __restrict__ bias, void* __restrict__ Yv, int ot_per,
    long xbs, long ybs, long wbs)
{
  __shared__ __align__(16) unsigned short Xl[192][68];   // 26112 B
  const int tid = threadIdx.x;
  const int b = blockIdx.z;
  const int n0 = blockIdx.x * 64;
  const unsigned short* Wf = Wf0 + (size_t)b * wbs;

  if (XBF) {
    const unsigned short* X = (const unsigned short*)Xv + (size_t)b * xbs;
#pragma unroll
    for (int i = 0; i < 12; ++i) {
      const int g = tid + i * 256;
      const int c = g >> 4, nq = (g & 15) * 4;
      *(unsigned long long*)&Xl[c][nq] =
          *(const unsigned long long*)&X[(size_t)c * NTOK + n0 + nq];
    }
  } else {
    const float* X = (const float*)Xv + (size_t)b * xbs;
#pragma unroll
    for (int i = 0; i < 12; ++i) {
      const int g = tid + i * 256;
      const int c = g >> 4, nq = (g & 15) * 4;
      float4 v = *(const float4*)&X[(size_t)c * NTOK + n0 + nq];
      unsigned short p[4] = {f2bf(v.x), f2bf(v.y), f2bf(v.z), f2bf(v.w)};
      *(unsigned long long*)&Xl[c][nq] = *(unsigned long long*)p;
    }
  }
  __syncthreads();

  const int lane = tid & 63;
  const int wv = tid >> 6;
  const int o_w = (wv >> 1) * 32;
  const int n_w = (wv & 1) * 32;
  const int j = lane & 31;
  const int hi = lane >> 5;

  bf16x8 bfr[12];
#pragma unroll
  for (int kk = 0; kk < 12; ++kk)
#pragma unroll
    for (int e = 0; e < 8; ++e)
      bfr[kk][e] = (short)Xl[kk * 16 + hi * 8 + e][n_w + j];

  for (int it = 0; it < ot_per; ++it) {
    const int o0 = it * 64;
    const unsigned short* wp =
        Wf + ((size_t)it * 1536 + hi * 64 + o_w + j) * 8;

    // 12-deep pipelined A-frag loads (cannot be sunk by the scheduler)
    bf16x8 a[12];
#pragma unroll
    for (int kk = 0; kk < 12; ++kk) {
      unsigned long long ad = (unsigned long long)(wp + kk * 1024);
      asm volatile("global_load_dwordx4 %0, %1, off"
                   : "=v"(a[kk]) : "v"(ad));
    }
    asm volatile("s_waitcnt vmcnt(0)" ::: "memory");
    __builtin_amdgcn_sched_barrier(0);

    f32x16 acc0, acc1;
#pragma unroll
    for (int i = 0; i < 16; ++i) { acc0[i] = 0.f; acc1[i] = 0.f; }
#pragma unroll
    for (int kp = 0; kp < 6; ++kp) {
      acc0 = __builtin_amdgcn_mfma_f32_32x32x16_bf16(a[2 * kp], bfr[2 * kp], acc0, 0, 0, 0);
      acc1 = __builtin_amdgcn_mfma_f32_32x32x16_bf16(a[2 * kp + 1], bfr[2 * kp + 1], acc1, 0, 0, 0);
    }

    if (OUTF32) {
      float* Y = (float*)Yv + (size_t)b * ybs;
#pragma unroll
      for (int r = 0; r < 16; ++r) {
        const int row = o_w + (r & 3) + 8 * (r >> 2) + 4 * hi;
        Y[(size_t)(o0 + row) * NTOK + n0 + n_w + j] =
            acc0[r] + acc1[r] + bias[o0 + row];
      }
    } else {
      unsigned short* Y = (unsigned short*)Yv + (size_t)b * ybs;
#pragma unroll
      for (int r = 0; r < 16; ++r) {
        const int row = o_w + (r & 3) + 8 * (r >> 2) + 4 * hi;
        Y[(size_t)(o0 + row) * NTOK + n0 + n_w + j] =
            f2bf(acc0[r] + acc1[r] + bias[o0 + row]);
      }
    }
  }
}

// ---------------------------------------------------------------------------
// K2: depthwise 3x3x3, pad 1, bf16 in/out, fp32 math; grid.z = batch.
// Rolling-store form (r17): VALU-issue-bound at its structural floor.
// ---------------------------------------------------------------------------
__global__ __launch_bounds__(256, 4) void k_dwconv(
    const unsigned short* __restrict__ in0,   // [2][576][8][64][64] bf16
    const float* __restrict__ wdw,            // [576][27]
    const float* __restrict__ bdw,            // [576]
    unsigned short* __restrict__ out0)        // [2][576][8][64][64] bf16
{
  __shared__ __align__(16) unsigned short s[8][18][76];
  const int tid = threadIdx.x;
  const int ch = blockIdx.y;
  const int h0 = blockIdx.x * 16;
  const size_t boff = (size_t)blockIdx.z * C3 * NTOK;
  const unsigned short* inch = in0 + boff + (size_t)ch * NTOK;

  for (int r = tid; r < 144; r += 256) {
    const int t = r / 18, rr = r % 18;
    s[t][rr][7] = 0;
    s[t][rr][72] = 0;
  }
  for (int idx = tid; idx < 144 * 8; idx += 256) {
    const int row = idx >> 3, seg = idx & 7;
    const int t = row / 18, rr = row % 18;
    const int h = h0 + rr - 1;
    u32x4 v = {0u, 0u, 0u, 0u};
    if (h >= 0 && h < 64)
      v = *(const u32x4*)&inch[t * 4096 + h * 64 + seg * 8];
    *(u32x4*)&s[t][rr][8 + seg * 8] = v;
  }
  float wr[27];
#pragma unroll
  for (int i = 0; i < 27; ++i) {
    union { float f; int v; } u;
    u.f = wdw[ch * 27 + i];
    u.v = __builtin_amdgcn_readfirstlane(u.v);
    wr[i] = u.f;
  }
  union { float f; int v; } ub;
  ub.f = bdw[ch];
  ub.v = __builtin_amdgcn_readfirstlane(ub.v);
  const float bias = ub.f;
  __syncthreads();

  const int wloc = tid & 63;
  const int hl0 = (tid >> 6) * 4;
  unsigned short* outch = out0 + boff + (size_t)ch * NTOK;

  float acc[8][4];
#pragma unroll
  for (int t = 0; t < 8; ++t)
#pragma unroll
    for (int i = 0; i < 4; ++i) acc[t][i] = 0.f;

#pragma unroll
  for (int tt = 0; tt < 8; ++tt) {
    float v[6][3];
#pragma unroll
    for (int r = 0; r < 6; ++r)
#pragma unroll
      for (int c = 0; c < 3; ++c)
        v[r][c] = bf2f(s[tt][hl0 + r][7 + wloc + c]);
#pragma unroll
    for (int p = 0; p < 3; ++p) {
      const int t = tt + 1 - p;
      if (t < 0 || t > 7) continue;   // compile-time pruned
#pragma unroll
      for (int hi = 0; hi < 4; ++hi) {
        float a = 0.f;
#pragma unroll
        for (int dh = 0; dh < 3; ++dh)
#pragma unroll
          for (int dw = 0; dw < 3; ++dw)
            a += wr[p * 9 + dh * 3 + dw] * v[hi + dh][dw];
        acc[t][hi] += a;
      }
    }
    if (tt >= 1) {
      const int t = tt - 1;
#pragma unroll
      for (int hi = 0; hi < 4; ++hi)
        outch[t * 4096 + (h0 + hl0 + hi) * 64 + wloc] = f2bf(acc[t][hi] + bias);
    }
  }
#pragma unroll
  for (int hi = 0; hi < 4; ++hi)
    outch[7 * 4096 + (h0 + hl0 + hi) * 64 + wloc] = f2bf(acc[7][hi] + bias);
}

// ---------------------------------------------------------------------------
// K3: Gram via MFMA, direct-from-global; partials to Sp (no atomics/zero-init).
// grid (32 chunks, 8 heads, 2 batches).
// ---------------------------------------------------------------------------
__global__ __launch_bounds__(256) void k_gram(
    const unsigned short* __restrict__ post0, float* __restrict__ Sp0)
{
  const int tid = threadIdx.x;
  const int h = blockIdx.y;
  const unsigned short* post = post0 + (size_t)blockIdx.z * C3 * NTOK;
  float* Sp = Sp0 + (size_t)blockIdx.z * HEADS * 32 * 640;
  const int lane = tid & 63;
  const int wv = tid >> 6;
  const int c = lane & 31;
  const int off = (lane >> 5) * 8;
  const unsigned short* q = post + (size_t)(h * HD + c) * NTOK;
  const unsigned short* k = post + (size_t)(192 + h * HD + c) * NTOK;

  __shared__ float Sl[24][25];
  __shared__ float nl[48];
  for (int i = tid; i < 600; i += 256) ((float*)Sl)[i] = 0.f;
  if (tid < 48) nl[tid] = 0.f;
  __syncthreads();

  f32x16 acc;
#pragma unroll
  for (int i = 0; i < 16; ++i) acc[i] = 0.f;
  float sqq = 0.f, sqk = 0.f;

  const int base = blockIdx.x * 1024 + wv * 256 + off;
#pragma unroll
  for (int i = 0; i < 16; ++i) {
    const int n = base + i * 16;
    bf16x8 a = *(const bf16x8*)&q[n];
    bf16x8 b = *(const bf16x8*)&k[n];
#pragma unroll
    for (int e = 0; e < 8; ++e) {
      float fa = bf2f((unsigned short)a[e]);
      float fb = bf2f((unsigned short)b[e]);
      sqq += fa * fa;
      sqk += fb * fb;
    }
    acc = __builtin_amdgcn_mfma_f32_32x32x16_bf16(a, b, acc, 0, 0, 0);
  }

  sqq += __shfl_down(sqq, 32, 64);
  sqk += __shfl_down(sqk, 32, 64);
  if (lane < 32 && c < 24) {
    atomicAdd(&nl[c], sqq);
    atomicAdd(&nl[24 + c], sqk);
  }
  if (c < 24) {
#pragma unroll
    for (int r = 0; r < 16; ++r) {
      const int row = (r & 3) + 8 * (r >> 2) + 4 * (lane >> 5);
      if (row < 24) atomicAdd(&Sl[row][c], acc[r]);
    }
  }
  __syncthreads();
  float* outp = Sp + ((size_t)h * 32 + blockIdx.x) * 640;
  for (int i = tid; i < 576; i += 256) outp[i] = Sl[i / 24][i % 24];
  if (tid < 48) outp[576 + tid] = nl[tid];
}

// ---------------------------------------------------------------------------
// K4: reduce Sp; attn = softmax(S*temp/(|q||k|)); Wcomb = projW @ attn,
// written DIRECTLY in MFMA-fragment layout. grid (8 heads, 2 batches).
// ---------------------------------------------------------------------------
__global__ __launch_bounds__(256) void k_attn_wfrag(
    const float* __restrict__ Sp0, const float* __restrict__ temp,
    const float* __restrict__ projw, unsigned short* __restrict__ wfc0)
{
  const int h = blockIdx.x;
  const int tid = threadIdx.x;
  const float* base = Sp0 + (size_t)blockIdx.y * HEADS * 32 * 640 +
                      (size_t)h * 32 * 640;
  unsigned short* wfc = wfc0 + (size_t)blockIdx.y * 3 * 1536 * 8;

  __shared__ float Ssum[24][25];
  __shared__ float attn[24][25];
  __shared__ float nqs[24], nks[24];

  for (int i = tid; i < 576; i += 256) {
    float a = 0.f;
#pragma unroll 4
    for (int ch = 0; ch < 32; ++ch) a += base[(size_t)ch * 640 + i];
    Ssum[i / 24][i % 24] = a;
  }
  if (tid < 48) {
    float a = 0.f;
#pragma unroll 4
    for (int ch = 0; ch < 32; ++ch) a += base[(size_t)ch * 640 + 576 + tid];
    float nv = fmaxf(sqrtf(a), 1e-12f);
    if (tid < 24) nqs[tid] = nv; else nks[tid - 24] = nv;
  }
  __syncthreads();
  if (tid < 24) {
    const int c = tid;
    const float tmp = temp[h];
    float row[24];
    float m = -1e30f;
#pragma unroll
    for (int d = 0; d < 24; ++d) {
      float v = Ssum[c][d] / (nqs[c] * nks[d]) * tmp;
      row[d] = v;
      m = fmaxf(m, v);
    }
    float ssum = 0.f;
#pragma unroll
    for (int d = 0; d < 24; ++d) { float e = __expf(row[d] - m); row[d] = e; ssum += e; }
    const float inv = 1.f / ssum;
#pragma unroll
    for (int d = 0; d < 24; ++d) attn[c][d] = row[d] * inv;
  }
  __syncthreads();
  for (int e = tid; e < 192 * 24; e += 256) {
    const int o = e / 24, d = e % 24;
    float a = 0.f;
#pragma unroll
    for (int c = 0; c < 24; ++c) a += projw[o * 192 + h * 24 + c] * attn[c][d];
    const int c2 = h * 24 + d;
    const int ot = o >> 6, ol = o & 63;
    const int kk = c2 >> 4, hi = (c2 >> 3) & 1, e2 = c2 & 7;
    wfc[(size_t)((((ot * 12 + kk) * 2 + hi) * 64) + ol) * 8 + e2] = f2bf(a);
  }
}

// ---------------------------------------------------------------------------
extern "C" void kernel_launch(void* const* d_in, const int* in_sizes, int n_in,
                              void* d_out, int out_size, void* d_ws, size_t ws_size,
                              hipStream_t stream) {
  const float* x      = (const float*)d_in[0];
  const float* qkv_w  = (const float*)d_in[1];
  const float* qkv_b  = (const float*)d_in[2];
  const float* dw_w   = (const float*)d_in[3];
  const float* dw_b   = (const float*)d_in[4];
  const float* temp   = (const float*)d_in[5];
  const float* proj_w = (const float*)d_in[6];
  const float* proj_b = (const float*)d_in[7];
  float* out = (float*)d_out;

  char* ws = (char*)d_ws;
  size_t off = 0;
  unsigned short* post = (unsigned short*)(ws + off);
  off += (size_t)2 * C3 * NTOK * sizeof(unsigned short);       // 75.5 MB
  unsigned short* pre = (unsigned short*)(ws + off);
  off += (size_t)2 * C3 * NTOK * sizeof(unsigned short);       // 75.5 MB
  float* Sp = (float*)(ws + off);                              // [2][8*32][640]
  off += (size_t)2 * HEADS * 32 * 640 * sizeof(float);         // 1.31 MB
  off = (off + 255) & ~(size_t)255;
  unsigned short* wfq = (unsigned short*)(ws + off);           // qkv W frags
  off += (size_t)9 * 1536 * 8 * sizeof(unsigned short);        // 221 KB
  unsigned short* wfc = (unsigned short*)(ws + off);           // [2] wcomb frags
  off += (size_t)2 * 3 * 1536 * 8 * sizeof(unsigned short);    // 147 KB

  k_wfrag<<<54, 256, 0, stream>>>(qkv_w, wfq, 9 * 1536);

  k_gemm_rr<0, 0><<<dim3(512, 1, 2), 256, 0, stream>>>(
      x, wfq, qkv_b, pre, 9, (long)CIN * NTOK, (long)C3 * NTOK, 0);

  k_dwconv<<<dim3(4, C3, 2), 256, 0, stream>>>(pre, dw_w, dw_b, post);

  k_gram<<<dim3(32, HEADS, 2), 256, 0, stream>>>(post, Sp);

  k_attn_wfrag<<<dim3(HEADS, 2), 256, 0, stream>>>(Sp, temp, proj_w, wfc);

  k_gemm_rr<1, 1><<<dim3(512, 1, 2), 256, 0, stream>>>(
      post + (size_t)384 * NTOK, wfc, proj_b, out, 3,
      (long)C3 * NTOK, (long)CIN * NTOK, (long)3 * 1536 * 8);
}